// Round 3
// baseline (1087.411 us; speedup 1.0000x reference)
//
#include <hip/hip_runtime.h>
#include <cstdint>
#include <cstddef>

#define L_SEQ 4096
#define BATCH 32
#define DIN 128
#define DLAT 512
#define TT 8                 // timesteps staged per LDS tile
#define NTILES (L_SEQ / TT)  // 512

__device__ __forceinline__ void async_copy16(const float* g, float* l) {
    // global -> LDS direct, 16 bytes per lane. LDS dest must be linear in lane id.
    __builtin_amdgcn_global_load_lds(
        (const __attribute__((address_space(1))) unsigned int*)g,
        (__attribute__((address_space(3))) unsigned int*)l,
        16, 0, 0);
}

__global__ __launch_bounds__(256) void rnn_fused(
    const float* __restrict__ X,   // [L, B, DIN]
    const float* __restrict__ h0,  // [B, DLAT]
    const float* __restrict__ wx,  // [DIN, DLAT]
    const float* __restrict__ wh,  // [DLAT]
    const float* __restrict__ bh,  // [DLAT]
    float* __restrict__ out)       // [L, B, DLAT]
{
    __shared__ float Xs[2][TT * DIN];  // 2 x 4 KiB

    const int tid = threadIdx.x;
    const int b   = blockIdx.x & 31;   // same-b blocks are stride-32 -> same XCD (mod 8)
    const int jg  = blockIdx.x >> 5;   // 0..7, 64 channels each
    const int c   = tid >> 2;          // channel within group, 0..63
    const int r   = tid & 3;           // K-slice index, 0..3
    const int j   = jg * 64 + c;       // latent channel 0..511

    // Preload this thread's wx slice: k = 8*r + 32*s + i  (s=0..3, i=0..7)
    float wxr[32];
#pragma unroll
    for (int s = 0; s < 4; ++s)
#pragma unroll
        for (int i = 0; i < 8; ++i)
            wxr[s * 8 + i] = wx[(8 * r + 32 * s + i) * DLAT + j];

    const float whj = wh[j];
    const float bhj = bh[j];
    float h = h0[(size_t)b * DLAT + j];

    // Staging: each thread copies 16B per tile. tt = tid>>5 (timestep in tile),
    // k4 = (tid&31)*4. LDS offset = tid*4 floats = linear in tid (required).
    const int tt = tid >> 5;
    const int k4 = (tid & 31) * 4;
    const float* gsrc0 = X + ((size_t)tt * BATCH + b) * DIN + k4;

    // Prologue: stage tile 0 into buffer 0.
    async_copy16(gsrc0, &Xs[0][0] + tid * 4);
    asm volatile("s_waitcnt vmcnt(0)" ::: "memory");
    __syncthreads();

    const size_t out_chan = (size_t)b * DLAT + j;

    for (int tile = 0; tile < NTILES; ++tile) {
        const int cur = tile & 1;
        if (tile + 1 < NTILES) {
            const float* g = gsrc0 + (size_t)(tile + 1) * TT * BATCH * DIN;
            async_copy16(g, &Xs[0][0] + (cur ^ 1) * (TT * DIN) + tid * 4);
        }

        const float* xb = &Xs[cur][0];
#pragma unroll
        for (int g4 = 0; g4 < 2; ++g4) {
            float hs = 0.f;
#pragma unroll
            for (int q = 0; q < 4; ++q) {
                const int t_in = g4 * 4 + q;
                const float* xt = xb + t_in * DIN + 8 * r;
                float a0 = 0.f, a1 = 0.f;
#pragma unroll
                for (int s = 0; s < 4; ++s) {
                    const float4 xa = *(const float4*)(xt + 32 * s);
                    const float4 xc = *(const float4*)(xt + 32 * s + 4);
                    a0 = fmaf(xa.x, wxr[s * 8 + 0], a0);
                    a1 = fmaf(xa.y, wxr[s * 8 + 1], a1);
                    a0 = fmaf(xa.z, wxr[s * 8 + 2], a0);
                    a1 = fmaf(xa.w, wxr[s * 8 + 3], a1);
                    a0 = fmaf(xc.x, wxr[s * 8 + 4], a0);
                    a1 = fmaf(xc.y, wxr[s * 8 + 5], a1);
                    a0 = fmaf(xc.z, wxr[s * 8 + 6], a0);
                    a1 = fmaf(xc.w, wxr[s * 8 + 7], a1);
                }
                float acc = a0 + a1;
                acc += __shfl_xor(acc, 1);
                acc += __shfl_xor(acc, 2);
                // h_t = h_{t-1} * wh + (dot + bh)
                h = fmaf(h, whj, acc + bhj);
                hs = (q == r) ? h : hs;   // lane r snapshots timestep t0+r
            }
            const int t = tile * TT + g4 * 4 + r;
            out[(size_t)t * (BATCH * DLAT) + out_chan] = tanhf(hs);
        }

        asm volatile("s_waitcnt vmcnt(0)" ::: "memory");
        __syncthreads();
    }
}

extern "C" void kernel_launch(void* const* d_in, const int* in_sizes, int n_in,
                              void* d_out, int out_size, void* d_ws, size_t ws_size,
                              hipStream_t stream) {
    const float* X  = (const float*)d_in[0];
    const float* h0 = (const float*)d_in[1];
    const float* wx = (const float*)d_in[2];
    const float* wh = (const float*)d_in[3];
    const float* bh = (const float*)d_in[4];
    float* out = (float*)d_out;

    rnn_fused<<<dim3(256), dim3(256), 0, stream>>>(X, h0, wx, wh, bh, out);
}

// Round 6
// 510.359 us; speedup vs baseline: 2.1307x; 2.1307x over previous
//
#include <hip/hip_runtime.h>
#include <cstdint>
#include <cstddef>

#define L_SEQ 4096
#define BATCH 32
#define DIN 128
#define DLAT 512
#define CHUNK 32
#define NCHUNK (L_SEQ / CHUNK)   // 128

__device__ __forceinline__ void async_copy16(const float* g, float* l) {
    // global -> LDS direct, 16 bytes per lane. LDS dest must be linear in lane id.
    __builtin_amdgcn_global_load_lds(
        (const __attribute__((address_space(1))) unsigned int*)g,
        (__attribute__((address_space(3))) unsigned int*)l,
        16, 0, 0);
}

// ---------------------------------------------------------------------------
// Kernel A: fused GEMM + chunk-local scan (from zero state).
// Writes PRE-tanh local values l_t into out (scratch), and the chunk-final
// local F[c,b,j] into ws (so kernel B never reads out across chunks -> no race).
// grid (NCHUNK, BATCH, 8), block 256. 4 threads per channel (K split 4-way).
// ---------------------------------------------------------------------------
__global__ __launch_bounds__(256) void rnn_local(
    const float* __restrict__ X,   // [L, B, DIN]
    const float* __restrict__ wx,  // [DIN, DLAT]
    const float* __restrict__ wh,  // [DLAT]
    const float* __restrict__ bh,  // [DLAT]
    float* __restrict__ out,       // [L, B, DLAT]  (scratch: pre-tanh locals)
    float* __restrict__ F)         // [NCHUNK, B, DLAT] chunk-final locals
{
    __shared__ float Xs[CHUNK * DIN];  // 16 KiB: whole chunk's X rows for batch b

    const int tid = threadIdx.x;
    const int c  = blockIdx.x;         // chunk
    const int b  = blockIdx.y;         // batch
    const int jg = blockIdx.z;         // channel group (64 channels)
    const int ch = tid >> 2;           // 0..63
    const int r  = tid & 3;            // K-slice 0..3
    const int j  = jg * 64 + ch;

    // Stage X[c*32 .. c*32+31, b, :] -> LDS, 4 shots of 8 timesteps each.
    // Shot s: ts = tid>>5 (0..7), k = (tid&31)*4. LDS float idx = s*1024 + tid*4
    // == (s*8 + ts)*128 + k  -> Xs[t*128 + k], linear in tid per shot (required).
    {
        const int ts  = tid >> 5;          // 0..7
        const int k16 = (tid & 31) * 4;    // 0..124
        const float* g0 = X + ((size_t)(c * CHUNK + ts) * BATCH + b) * DIN + k16;
        float* l0 = Xs + tid * 4;
#pragma unroll
        for (int s = 0; s < 4; ++s)
            async_copy16(g0 + (size_t)s * 8 * BATCH * DIN, l0 + s * 1024);
    }

    // wx slice: k = 8*r + 32*s + i  (s=0..3, i=0..7) -> 32 VGPRs
    float wxr[32];
#pragma unroll
    for (int s = 0; s < 4; ++s)
#pragma unroll
        for (int i = 0; i < 8; ++i)
            wxr[s * 8 + i] = wx[(8 * r + 32 * s + i) * DLAT + j];

    const float whj = wh[j];
    const float bhj = bh[j];

    asm volatile("s_waitcnt vmcnt(0)" ::: "memory");
    __syncthreads();

    float l = 0.f;  // chunk-local state, starts from zero
    const size_t ob = (size_t)b * DLAT + j;

    for (int g = 0; g < 8; ++g) {
        float snap = 0.f;
#pragma unroll
        for (int q = 0; q < 4; ++q) {
            const float* xt = Xs + (g * 4 + q) * DIN + 8 * r;
            float a0 = 0.f, a1 = 0.f;
#pragma unroll
            for (int s = 0; s < 4; ++s) {
                const float4 xa = *(const float4*)(xt + 32 * s);
                const float4 xc = *(const float4*)(xt + 32 * s + 4);
                a0 = fmaf(xa.x, wxr[s * 8 + 0], a0);
                a1 = fmaf(xa.y, wxr[s * 8 + 1], a1);
                a0 = fmaf(xa.z, wxr[s * 8 + 2], a0);
                a1 = fmaf(xa.w, wxr[s * 8 + 3], a1);
                a0 = fmaf(xc.x, wxr[s * 8 + 4], a0);
                a1 = fmaf(xc.y, wxr[s * 8 + 5], a1);
                a0 = fmaf(xc.z, wxr[s * 8 + 6], a0);
                a1 = fmaf(xc.w, wxr[s * 8 + 7], a1);
            }
            float acc = a0 + a1;
            acc += __shfl_xor(acc, 1);
            acc += __shfl_xor(acc, 2);
            l = fmaf(l, whj, acc + bhj);
            snap = (q == r) ? l : snap;   // lane r keeps timestep 4g+r
        }
        const int t = c * CHUNK + g * 4 + r;
        out[(size_t)t * (BATCH * DLAT) + ob] = snap;
    }

    // After the loop every lane of a channel holds l = local value at depth 31.
    if (r == 0)
        F[((size_t)c * BATCH + b) * DLAT + j] = l;
}

// ---------------------------------------------------------------------------
// Kernel B: rebuild chunk-start state H_c from chunk-final locals F (in ws),
// then in-place fixup: out_t = tanh(l_t + wh^{d+1} * H_c).
// grid (NCHUNK/2, BATCH), block 256 = 2 chunks x 128 threads x 4 channels.
// Reads `out` only within its own chunk -> no cross-block race.
// ---------------------------------------------------------------------------
__global__ __launch_bounds__(256) void rnn_fix(
    const float* __restrict__ h0,  // [B, DLAT]
    const float* __restrict__ wh,  // [DLAT]
    const float* __restrict__ F,   // [NCHUNK, B, DLAT]
    float* __restrict__ out)       // [L, B, DLAT] in-place
{
    const int tid = threadIdx.x;
    const int sub = tid >> 7;              // 0/1 -> which chunk
    const int tl  = tid & 127;
    const int c   = blockIdx.x * 2 + sub;  // 0..127
    const int b   = blockIdx.y;
    const int j4  = tl * 4;                // channel base, float4 per thread

    const size_t chb = (size_t)b * DLAT + j4;

    float4 h4 = *(const float4*)(h0 + chb);
    float4 w4 = *(const float4*)(wh + j4);
    float Hv[4] = {h4.x, h4.y, h4.z, h4.w};
    float wv[4] = {w4.x, w4.y, w4.z, w4.w};

    // whC = wh^32 via 5 squarings; always > 0 (even power) -> inf H keeps sign.
    float wc[4];
#pragma unroll
    for (int k = 0; k < 4; ++k) {
        float t = wv[k];
        t = t * t; t = t * t; t = t * t; t = t * t; t = t * t;
        wc[k] = t;
    }

    // History: H_c = fold over chunks 0..c-1 of H = whC*H + F_cc.
    int cc = 0;
    while (cc + 8 <= c) {
        float4 Fv[8];
#pragma unroll
        for (int i = 0; i < 8; ++i)
            Fv[i] = *(const float4*)(F + ((size_t)(cc + i) * BATCH + b) * DLAT + j4);
#pragma unroll
        for (int i = 0; i < 8; ++i) {
            Hv[0] = fmaf(Hv[0], wc[0], Fv[i].x);
            Hv[1] = fmaf(Hv[1], wc[1], Fv[i].y);
            Hv[2] = fmaf(Hv[2], wc[2], Fv[i].z);
            Hv[3] = fmaf(Hv[3], wc[3], Fv[i].w);
        }
        cc += 8;
    }
    for (; cc < c; ++cc) {
        const float4 Fv = *(const float4*)(F + ((size_t)cc * BATCH + b) * DLAT + j4);
        Hv[0] = fmaf(Hv[0], wc[0], Fv.x);
        Hv[1] = fmaf(Hv[1], wc[1], Fv.y);
        Hv[2] = fmaf(Hv[2], wc[2], Fv.z);
        Hv[3] = fmaf(Hv[3], wc[3], Fv.w);
    }

    // Fixup + tanh, in place. sc_d = wh^{d+1}; no inf*0 or inf-inf paths.
    float sc[4] = {wv[0], wv[1], wv[2], wv[3]};
    for (int d = 0; d < CHUNK; ++d) {
        const size_t off = ((size_t)(c * CHUNK + d) * BATCH + b) * DLAT + j4;
        float4 l4 = *(const float4*)(out + off);
        float4 res;
        res.x = tanhf(fmaf(sc[0], Hv[0], l4.x));
        res.y = tanhf(fmaf(sc[1], Hv[1], l4.y));
        res.z = tanhf(fmaf(sc[2], Hv[2], l4.z));
        res.w = tanhf(fmaf(sc[3], Hv[3], l4.w));
        *(float4*)(out + off) = res;
        sc[0] *= wv[0]; sc[1] *= wv[1]; sc[2] *= wv[2]; sc[3] *= wv[3];
    }
}

extern "C" void kernel_launch(void* const* d_in, const int* in_sizes, int n_in,
                              void* d_out, int out_size, void* d_ws, size_t ws_size,
                              hipStream_t stream) {
    const float* X  = (const float*)d_in[0];
    const float* h0 = (const float*)d_in[1];
    const float* wx = (const float*)d_in[2];
    const float* wh = (const float*)d_in[3];
    const float* bh = (const float*)d_in[4];
    float* out = (float*)d_out;
    float* F   = (float*)d_ws;   // NCHUNK*BATCH*DLAT floats = 8 MiB

    rnn_local<<<dim3(NCHUNK, BATCH, 8), dim3(256), 0, stream>>>(X, wx, wh, bh, out, F);
    rnn_fix<<<dim3(NCHUNK / 2, BATCH), dim3(256), 0, stream>>>(h0, wh, F, out);
}

// Round 7
// 438.283 us; speedup vs baseline: 2.4811x; 1.1645x over previous
//
#include <hip/hip_runtime.h>
#include <cstdint>
#include <cstddef>

#define L_SEQ 4096
#define BATCH 32
#define DIN 128
#define DLAT 512
#define CHUNK 32
#define NCHUNK (L_SEQ / CHUNK)   // 128

__device__ __forceinline__ void async_copy16(const float* g, float* l) {
    __builtin_amdgcn_global_load_lds(
        (const __attribute__((address_space(1))) unsigned int*)g,
        (__attribute__((address_space(3))) unsigned int*)l,
        16, 0, 0);
}

// Quad-perm DPP cross-lane adds (lanes tid&3 form a DPP quad).
// xor1: perm [1,0,3,2] = 0xB1 ; xor2: perm [2,3,0,1] = 0x4E. Pure VALU.
__device__ __forceinline__ float dpp_add_xor1(float x) {
    int r = __builtin_amdgcn_update_dpp(0, __builtin_bit_cast(int, x),
                                        0xB1, 0xF, 0xF, true);
    return x + __builtin_bit_cast(float, r);
}
__device__ __forceinline__ float dpp_add_xor2(float x) {
    int r = __builtin_amdgcn_update_dpp(0, __builtin_bit_cast(int, x),
                                        0x4E, 0xF, 0xF, true);
    return x + __builtin_bit_cast(float, r);
}

// ---------------------------------------------------------------------------
// Kernel A: fused GEMM + chunk-local scan, 2 channels per thread.
// grid (NCHUNK, BATCH, 4), block 256. Thread: r = tid&3 (K-slice), ch = tid>>2,
// channels j0 = jg*128+ch and j1 = j0+64. Same X float4s feed both channels.
// ---------------------------------------------------------------------------
__global__ __launch_bounds__(256, 4) void rnn_local(
    const float* __restrict__ X,   // [L, B, DIN]
    const float* __restrict__ wx,  // [DIN, DLAT]
    const float* __restrict__ wh,  // [DLAT]
    const float* __restrict__ bh,  // [DLAT]
    float* __restrict__ out,       // [L, B, DLAT]  (scratch: pre-tanh locals)
    float* __restrict__ F)         // [NCHUNK, B, DLAT] chunk-final locals
{
    __shared__ float Xs[CHUNK * DIN];  // 16 KiB

    const int tid = threadIdx.x;
    const int c  = blockIdx.x;
    const int b  = blockIdx.y;
    const int jg = blockIdx.z;         // 0..3, 128 channels per group
    const int ch = tid >> 2;           // 0..63
    const int r  = tid & 3;            // K-slice 0..3
    const int j0 = jg * 128 + ch;
    const int j1 = j0 + 64;

    // Stage X[c*32..c*32+31, b, :] -> LDS, 4 shots of 8 timesteps.
    // Shot s: ts = tid>>5, k = (tid&31)*4; LDS float idx s*1024 + tid*4
    // == (s*8+ts)*128 + k -> Xs[t*128+k], linear in tid per shot.
    {
        const int ts  = tid >> 5;
        const int k16 = (tid & 31) * 4;
        const float* g0 = X + ((size_t)(c * CHUNK + ts) * BATCH + b) * DIN + k16;
        float* l0 = Xs + tid * 4;
#pragma unroll
        for (int s = 0; s < 4; ++s)
            async_copy16(g0 + (size_t)s * 8 * BATCH * DIN, l0 + s * 1024);
    }

    // wx slices for both channels: k = 8*r + 32*s + i
    float wx0[32], wx1[32];
#pragma unroll
    for (int s = 0; s < 4; ++s)
#pragma unroll
        for (int i = 0; i < 8; ++i) {
            const int k = 8 * r + 32 * s + i;
            wx0[s * 8 + i] = wx[(size_t)k * DLAT + j0];
            wx1[s * 8 + i] = wx[(size_t)k * DLAT + j1];
        }

    const float wh0 = wh[j0], wh1 = wh[j1];
    const float bh0 = bh[j0], bh1 = bh[j1];

    asm volatile("s_waitcnt vmcnt(0)" ::: "memory");
    __syncthreads();

    float l0 = 0.f, l1 = 0.f;
    const size_t ob0 = (size_t)b * DLAT + j0;
    const size_t ob1 = (size_t)b * DLAT + j1;

    for (int g = 0; g < 8; ++g) {
        float snap0 = 0.f, snap1 = 0.f;
#pragma unroll
        for (int q = 0; q < 4; ++q) {
            const float* xt = Xs + (g * 4 + q) * DIN + 8 * r;
            float a0 = 0.f, a1 = 0.f, b0 = 0.f, b1 = 0.f;
#pragma unroll
            for (int s = 0; s < 4; ++s) {
                const float4 xa = *(const float4*)(xt + 32 * s);
                const float4 xc = *(const float4*)(xt + 32 * s + 4);
                a0 = fmaf(xa.x, wx0[s * 8 + 0], a0);
                b0 = fmaf(xa.x, wx1[s * 8 + 0], b0);
                a1 = fmaf(xa.y, wx0[s * 8 + 1], a1);
                b1 = fmaf(xa.y, wx1[s * 8 + 1], b1);
                a0 = fmaf(xa.z, wx0[s * 8 + 2], a0);
                b0 = fmaf(xa.z, wx1[s * 8 + 2], b0);
                a1 = fmaf(xa.w, wx0[s * 8 + 3], a1);
                b1 = fmaf(xa.w, wx1[s * 8 + 3], b1);
                a0 = fmaf(xc.x, wx0[s * 8 + 4], a0);
                b0 = fmaf(xc.x, wx1[s * 8 + 4], b0);
                a1 = fmaf(xc.y, wx0[s * 8 + 5], a1);
                b1 = fmaf(xc.y, wx1[s * 8 + 5], b1);
                a0 = fmaf(xc.z, wx0[s * 8 + 6], a0);
                b0 = fmaf(xc.z, wx1[s * 8 + 6], b0);
                a1 = fmaf(xc.w, wx0[s * 8 + 7], a1);
                b1 = fmaf(xc.w, wx1[s * 8 + 7], b1);
            }
            float acc0 = a0 + a1;
            float acc1 = b0 + b1;
            acc0 = dpp_add_xor1(acc0); acc0 = dpp_add_xor2(acc0);
            acc1 = dpp_add_xor1(acc1); acc1 = dpp_add_xor2(acc1);
            l0 = fmaf(l0, wh0, acc0 + bh0);
            l1 = fmaf(l1, wh1, acc1 + bh1);
            snap0 = (q == r) ? l0 : snap0;
            snap1 = (q == r) ? l1 : snap1;
        }
        const int t = c * CHUNK + g * 4 + r;
        const size_t row = (size_t)t * (BATCH * DLAT);
        out[row + ob0] = snap0;
        out[row + ob1] = snap1;
    }

    if (r == 0) {
        F[((size_t)c * BATCH + b) * DLAT + j0] = l0;
        F[((size_t)c * BATCH + b) * DLAT + j1] = l1;
    }
}

// ---------------------------------------------------------------------------
// Kernel B: rebuild chunk-start state H_c from F (in ws), in-place fixup:
// out_t = tanh(l_t + wh^{d+1} * H_c). grid (NCHUNK/2, BATCH), block 256.
// ---------------------------------------------------------------------------
__global__ __launch_bounds__(256) void rnn_fix(
    const float* __restrict__ h0,  // [B, DLAT]
    const float* __restrict__ wh,  // [DLAT]
    const float* __restrict__ F,   // [NCHUNK, B, DLAT]
    float* __restrict__ out)       // [L, B, DLAT] in-place
{
    const int tid = threadIdx.x;
    const int sub = tid >> 7;
    const int tl  = tid & 127;
    const int c   = blockIdx.x * 2 + sub;
    const int b   = blockIdx.y;
    const int j4  = tl * 4;

    const size_t chb = (size_t)b * DLAT + j4;

    float4 h4 = *(const float4*)(h0 + chb);
    float4 w4 = *(const float4*)(wh + j4);
    float Hv[4] = {h4.x, h4.y, h4.z, h4.w};
    float wv[4] = {w4.x, w4.y, w4.z, w4.w};

    // wh^32 via 5 squarings; even power > 0 -> inf H keeps sign.
    float wc[4];
#pragma unroll
    for (int k = 0; k < 4; ++k) {
        float t = wv[k];
        t = t * t; t = t * t; t = t * t; t = t * t; t = t * t;
        wc[k] = t;
    }

    int cc = 0;
    while (cc + 8 <= c) {
        float4 Fv[8];
#pragma unroll
        for (int i = 0; i < 8; ++i)
            Fv[i] = *(const float4*)(F + ((size_t)(cc + i) * BATCH + b) * DLAT + j4);
#pragma unroll
        for (int i = 0; i < 8; ++i) {
            Hv[0] = fmaf(Hv[0], wc[0], Fv[i].x);
            Hv[1] = fmaf(Hv[1], wc[1], Fv[i].y);
            Hv[2] = fmaf(Hv[2], wc[2], Fv[i].z);
            Hv[3] = fmaf(Hv[3], wc[3], Fv[i].w);
        }
        cc += 8;
    }
    for (; cc < c; ++cc) {
        const float4 Fv = *(const float4*)(F + ((size_t)cc * BATCH + b) * DLAT + j4);
        Hv[0] = fmaf(Hv[0], wc[0], Fv.x);
        Hv[1] = fmaf(Hv[1], wc[1], Fv.y);
        Hv[2] = fmaf(Hv[2], wc[2], Fv.z);
        Hv[3] = fmaf(Hv[3], wc[3], Fv.w);
    }

    float sc[4] = {wv[0], wv[1], wv[2], wv[3]};
    for (int d = 0; d < CHUNK; ++d) {
        const size_t off = ((size_t)(c * CHUNK + d) * BATCH + b) * DLAT + j4;
        float4 l4 = *(const float4*)(out + off);
        float4 res;
        res.x = tanhf(fmaf(sc[0], Hv[0], l4.x));
        res.y = tanhf(fmaf(sc[1], Hv[1], l4.y));
        res.z = tanhf(fmaf(sc[2], Hv[2], l4.z));
        res.w = tanhf(fmaf(sc[3], Hv[3], l4.w));
        *(float4*)(out + off) = res;
        sc[0] *= wv[0]; sc[1] *= wv[1]; sc[2] *= wv[2]; sc[3] *= wv[3];
    }
}

extern "C" void kernel_launch(void* const* d_in, const int* in_sizes, int n_in,
                              void* d_out, int out_size, void* d_ws, size_t ws_size,
                              hipStream_t stream) {
    const float* X  = (const float*)d_in[0];
    const float* h0 = (const float*)d_in[1];
    const float* wx = (const float*)d_in[2];
    const float* wh = (const float*)d_in[3];
    const float* bh = (const float*)d_in[4];
    float* out = (float*)d_out;
    float* F   = (float*)d_ws;   // NCHUNK*BATCH*DLAT floats = 8 MiB

    rnn_local<<<dim3(NCHUNK, BATCH, 4), dim3(256), 0, stream>>>(X, wx, wh, bh, out, F);
    rnn_fix<<<dim3(NCHUNK / 2, BATCH), dim3(256), 0, stream>>>(h0, wh, F, out);
}

// Round 8
// 367.003 us; speedup vs baseline: 2.9629x; 1.1942x over previous
//
#include <hip/hip_runtime.h>
#include <cstdint>
#include <cstddef>

#define L_SEQ 4096
#define BATCH 32
#define DIN 128
#define DLAT 512
#define CHUNK 32
#define NCHUNK (L_SEQ / CHUNK)   // 128
#define MC 4                     // chunks per block in kernel A
#define NCH 4                    // channels per thread in kernel A

__device__ __forceinline__ void async_copy16(const float* g, float* l) {
    __builtin_amdgcn_global_load_lds(
        (const __attribute__((address_space(1))) unsigned int*)g,
        (__attribute__((address_space(3))) unsigned int*)l,
        16, 0, 0);
}

// Quad-perm DPP cross-lane adds (lanes tid&3 form a DPP quad). Pure VALU.
__device__ __forceinline__ float dpp_add_xor1(float x) {
    int r = __builtin_amdgcn_update_dpp(0, __builtin_bit_cast(int, x),
                                        0xB1, 0xF, 0xF, true);
    return x + __builtin_bit_cast(float, r);
}
__device__ __forceinline__ float dpp_add_xor2(float x) {
    int r = __builtin_amdgcn_update_dpp(0, __builtin_bit_cast(int, x),
                                        0x4E, 0xF, 0xF, true);
    return x + __builtin_bit_cast(float, r);
}

// ---------------------------------------------------------------------------
// Kernel A: fused GEMM + chunk-local scan. 4 channels/thread, 4 chunks/block,
// double-buffered LDS staging. grid (NCHUNK/MC, BATCH, 2), block 256.
// Thread: r = tid&3 (K-slice), ch = tid>>2; channels j_n = jg*256 + n*64 + ch.
// ---------------------------------------------------------------------------
__global__ __launch_bounds__(256, 2) void rnn_local(
    const float* __restrict__ X,   // [L, B, DIN]
    const float* __restrict__ wx,  // [DIN, DLAT]
    const float* __restrict__ wh,  // [DLAT]
    const float* __restrict__ bh,  // [DLAT]
    float* __restrict__ out,       // [L, B, DLAT]  (scratch: pre-tanh locals)
    float* __restrict__ F)         // [NCHUNK, B, DLAT] chunk-final locals
{
    __shared__ float Xs[2][CHUNK * DIN];  // 2 x 16 KiB, double buffer

    const int tid = threadIdx.x;
    const int c0 = blockIdx.x * MC;    // first chunk of this block
    const int b  = blockIdx.y;
    const int jg = blockIdx.z;         // 0..1, 256 channels per group
    const int ch = tid >> 2;           // 0..63
    const int r  = tid & 3;            // K-slice 0..3

    // Staging addresses: shot s stages timesteps 8s..8s+7 of chunk c.
    // ts = tid>>5 (0..7), k = (tid&31)*4. LDS float idx = s*1024 + tid*4
    // == (8s+ts)*128 + k  -> Xs[buf][t*128+k], linear in tid per shot.
    const int ts  = tid >> 5;
    const int k16 = (tid & 31) * 4;
    const float* gbase = X + ((size_t)ts * BATCH + b) * DIN + k16;

#define STAGE(cc, buf)                                                          \
    {                                                                           \
        const float* g0 = gbase + (size_t)(cc) * CHUNK * BATCH * DIN;           \
        float* l0 = &Xs[buf][0] + tid * 4;                                      \
        _Pragma("unroll")                                                       \
        for (int s = 0; s < 4; ++s)                                             \
            async_copy16(g0 + (size_t)s * 8 * BATCH * DIN, l0 + s * 1024);      \
    }

    // Prologue: stage first chunk into buffer 0, load weights meanwhile.
    STAGE(c0, 0)

    // wx slices for 4 channels: k = 8*r + 32*s + i
    float wxr[NCH][32];
    int jn[NCH];
    float whn[NCH], bhn[NCH];
#pragma unroll
    for (int n = 0; n < NCH; ++n) {
        jn[n] = jg * 256 + n * 64 + ch;
        whn[n] = wh[jn[n]];
        bhn[n] = bh[jn[n]];
    }
#pragma unroll
    for (int s = 0; s < 4; ++s)
#pragma unroll
        for (int i = 0; i < 8; ++i) {
            const size_t krow = (size_t)(8 * r + 32 * s + i) * DLAT;
#pragma unroll
            for (int n = 0; n < NCH; ++n)
                wxr[n][s * 8 + i] = wx[krow + jn[n]];
        }

    asm volatile("s_waitcnt vmcnt(0)" ::: "memory");
    __syncthreads();

    for (int m = 0; m < MC; ++m) {
        const int c   = c0 + m;
        const int buf = m & 1;
        if (m + 1 < MC)
            STAGE(c + 1, (m + 1) & 1)   // async into other buffer during compute

        float l[NCH] = {0.f, 0.f, 0.f, 0.f};

        for (int g = 0; g < 8; ++g) {
            float snap[NCH] = {0.f, 0.f, 0.f, 0.f};
#pragma unroll
            for (int q = 0; q < 4; ++q) {
                const float* xt = &Xs[buf][0] + (g * 4 + q) * DIN + 8 * r;
                float acc[NCH] = {0.f, 0.f, 0.f, 0.f};
#pragma unroll
                for (int s = 0; s < 4; ++s) {
                    const float4 xa = *(const float4*)(xt + 32 * s);
                    const float4 xc = *(const float4*)(xt + 32 * s + 4);
#pragma unroll
                    for (int n = 0; n < NCH; ++n) {
                        acc[n] = fmaf(xa.x, wxr[n][s * 8 + 0], acc[n]);
                        acc[n] = fmaf(xa.y, wxr[n][s * 8 + 1], acc[n]);
                        acc[n] = fmaf(xa.z, wxr[n][s * 8 + 2], acc[n]);
                        acc[n] = fmaf(xa.w, wxr[n][s * 8 + 3], acc[n]);
                        acc[n] = fmaf(xc.x, wxr[n][s * 8 + 4], acc[n]);
                        acc[n] = fmaf(xc.y, wxr[n][s * 8 + 5], acc[n]);
                        acc[n] = fmaf(xc.z, wxr[n][s * 8 + 6], acc[n]);
                        acc[n] = fmaf(xc.w, wxr[n][s * 8 + 7], acc[n]);
                    }
                }
#pragma unroll
                for (int n = 0; n < NCH; ++n) {
                    float a = dpp_add_xor1(acc[n]);
                    a = dpp_add_xor2(a);
                    l[n] = fmaf(l[n], whn[n], a + bhn[n]);
                    snap[n] = (q == r) ? l[n] : snap[n];
                }
            }
            const int t = c * CHUNK + g * 4 + r;
            const size_t row = (size_t)t * (BATCH * DLAT) + (size_t)b * DLAT;
#pragma unroll
            for (int n = 0; n < NCH; ++n)
                out[row + jn[n]] = snap[n];
        }

        if (r == 0) {
            const size_t fb = ((size_t)c * BATCH + b) * DLAT;
#pragma unroll
            for (int n = 0; n < NCH; ++n)
                F[fb + jn[n]] = l[n];
        }

        asm volatile("s_waitcnt vmcnt(0)" ::: "memory");
        __syncthreads();
    }
#undef STAGE
}

// ---------------------------------------------------------------------------
// Kernel B0: sequential prefix over chunks -> Hpre[c] = state entering chunk c.
// grid (BATCH), block 128 (thread owns float4 of channels). Tiny.
// ---------------------------------------------------------------------------
__global__ __launch_bounds__(128) void rnn_prefix(
    const float* __restrict__ h0,   // [B, DLAT]
    const float* __restrict__ wh,   // [DLAT]
    const float* __restrict__ F,    // [NCHUNK, B, DLAT]
    float* __restrict__ Hpre)       // [NCHUNK, B, DLAT]
{
    const int b  = blockIdx.x;
    const int j4 = threadIdx.x * 4;
    const size_t cb = (size_t)b * DLAT + j4;

    float4 w4 = *(const float4*)(wh + j4);
    float wv[4] = {w4.x, w4.y, w4.z, w4.w};
    float wc[4];
#pragma unroll
    for (int k = 0; k < 4; ++k) {
        float t = wv[k];
        t = t * t; t = t * t; t = t * t; t = t * t; t = t * t;  // wh^32 (>0)
        wc[k] = t;
    }

    float4 h4 = *(const float4*)(h0 + cb);
    float Hv[4] = {h4.x, h4.y, h4.z, h4.w};

    for (int cg = 0; cg < NCHUNK / 4; ++cg) {
        float4 Fv[4];
#pragma unroll
        for (int i = 0; i < 4; ++i)
            Fv[i] = *(const float4*)(F + (size_t)(cg * 4 + i) * (BATCH * DLAT) + cb);
#pragma unroll
        for (int i = 0; i < 4; ++i) {
            float4 o = {Hv[0], Hv[1], Hv[2], Hv[3]};
            *(float4*)(Hpre + (size_t)(cg * 4 + i) * (BATCH * DLAT) + cb) = o;
            Hv[0] = fmaf(Hv[0], wc[0], Fv[i].x);
            Hv[1] = fmaf(Hv[1], wc[1], Fv[i].y);
            Hv[2] = fmaf(Hv[2], wc[2], Fv[i].z);
            Hv[3] = fmaf(Hv[3], wc[3], Fv[i].w);
        }
    }
}

// ---------------------------------------------------------------------------
// Kernel C: pure streaming fixup: out_t = tanh(l_t + wh^{d+1} * Hpre[c]).
// grid (NCHUNK/2, BATCH), block 256 = 2 chunks x 128 threads x float4.
// ---------------------------------------------------------------------------
__global__ __launch_bounds__(256) void rnn_fix2(
    const float* __restrict__ wh,    // [DLAT]
    const float* __restrict__ Hpre,  // [NCHUNK, B, DLAT]
    float* __restrict__ out)         // [L, B, DLAT] in-place
{
    const int tid = threadIdx.x;
    const int c   = blockIdx.x * 2 + (tid >> 7);
    const int b   = blockIdx.y;
    const int j4  = (tid & 127) * 4;
    const size_t cb = (size_t)b * DLAT + j4;

    float4 w4 = *(const float4*)(wh + j4);
    float4 H4 = *(const float4*)(Hpre + (size_t)c * (BATCH * DLAT) + cb);
    float wv[4] = {w4.x, w4.y, w4.z, w4.w};
    float Hv[4] = {H4.x, H4.y, H4.z, H4.w};

    float sc[4] = {wv[0], wv[1], wv[2], wv[3]};
#pragma unroll 4
    for (int d = 0; d < CHUNK; ++d) {
        const size_t off = ((size_t)(c * CHUNK + d) * BATCH + b) * DLAT + j4;
        float4 l4 = *(const float4*)(out + off);
        float4 res;
        res.x = tanhf(fmaf(sc[0], Hv[0], l4.x));
        res.y = tanhf(fmaf(sc[1], Hv[1], l4.y));
        res.z = tanhf(fmaf(sc[2], Hv[2], l4.z));
        res.w = tanhf(fmaf(sc[3], Hv[3], l4.w));
        *(float4*)(out + off) = res;
        sc[0] *= wv[0]; sc[1] *= wv[1]; sc[2] *= wv[2]; sc[3] *= wv[3];
    }
}

// Fallback (ws too small for Hpre): fold H per block from F, as in round 6.
__global__ __launch_bounds__(256) void rnn_fix(
    const float* __restrict__ h0, const float* __restrict__ wh,
    const float* __restrict__ F, float* __restrict__ out)
{
    const int tid = threadIdx.x;
    const int c   = blockIdx.x * 2 + (tid >> 7);
    const int b   = blockIdx.y;
    const int j4  = (tid & 127) * 4;
    const size_t cb = (size_t)b * DLAT + j4;

    float4 h4 = *(const float4*)(h0 + cb);
    float4 w4 = *(const float4*)(wh + j4);
    float Hv[4] = {h4.x, h4.y, h4.z, h4.w};
    float wv[4] = {w4.x, w4.y, w4.z, w4.w};
    float wc[4];
#pragma unroll
    for (int k = 0; k < 4; ++k) {
        float t = wv[k];
        t = t * t; t = t * t; t = t * t; t = t * t; t = t * t;
        wc[k] = t;
    }
    for (int cc = 0; cc < c; ++cc) {
        const float4 Fv = *(const float4*)(F + ((size_t)cc * BATCH + b) * DLAT + j4);
        Hv[0] = fmaf(Hv[0], wc[0], Fv.x);
        Hv[1] = fmaf(Hv[1], wc[1], Fv.y);
        Hv[2] = fmaf(Hv[2], wc[2], Fv.z);
        Hv[3] = fmaf(Hv[3], wc[3], Fv.w);
    }
    float sc[4] = {wv[0], wv[1], wv[2], wv[3]};
    for (int d = 0; d < CHUNK; ++d) {
        const size_t off = ((size_t)(c * CHUNK + d) * BATCH + b) * DLAT + j4;
        float4 l4 = *(const float4*)(out + off);
        float4 res;
        res.x = tanhf(fmaf(sc[0], Hv[0], l4.x));
        res.y = tanhf(fmaf(sc[1], Hv[1], l4.y));
        res.z = tanhf(fmaf(sc[2], Hv[2], l4.z));
        res.w = tanhf(fmaf(sc[3], Hv[3], l4.w));
        *(float4*)(out + off) = res;
        sc[0] *= wv[0]; sc[1] *= wv[1]; sc[2] *= wv[2]; sc[3] *= wv[3];
    }
}

extern "C" void kernel_launch(void* const* d_in, const int* in_sizes, int n_in,
                              void* d_out, int out_size, void* d_ws, size_t ws_size,
                              hipStream_t stream) {
    const float* X  = (const float*)d_in[0];
    const float* h0 = (const float*)d_in[1];
    const float* wx = (const float*)d_in[2];
    const float* wh = (const float*)d_in[3];
    const float* bh = (const float*)d_in[4];
    float* out = (float*)d_out;

    const size_t seg = (size_t)NCHUNK * BATCH * DLAT;  // 2M floats = 8 MiB
    float* F    = (float*)d_ws;
    float* Hpre = F + seg;

    rnn_local<<<dim3(NCHUNK / MC, BATCH, 2), dim3(256), 0, stream>>>(X, wx, wh, bh, out, F);
    if (ws_size >= 2 * seg * sizeof(float)) {
        rnn_prefix<<<dim3(BATCH), dim3(128), 0, stream>>>(h0, wh, F, Hpre);
        rnn_fix2<<<dim3(NCHUNK / 2, BATCH), dim3(256), 0, stream>>>(wh, Hpre, out);
    } else {
        rnn_fix<<<dim3(NCHUNK / 2, BATCH), dim3(256), 0, stream>>>(h0, wh, F, out);
    }
}